// Round 5
// baseline (609.387 us; speedup 1.0000x reference)
//
#include <hip/hip_runtime.h>
#include <math.h>

#define BB   128
#define NIN  512
#define NH   1024
#define LCTX 512
#define DD   1024
#define G4   4096
#define KG   1536
#define KO   2048

#define SK_G 16
#define SK_T 32
#define SK_O 32

#define CHUNKS 8
#define NPART  (CHUNKS * 4)
#define RB 4

__device__ __forceinline__ float sigf(float x) { return 1.0f / (1.0f + __expf(-x)); }

#define FMA4(A4, a, B4)                       \
    (A4).x = fmaf((a), (B4).x, (A4).x);       \
    (A4).y = fmaf((a), (B4).y, (A4).y);       \
    (A4).z = fmaf((a), (B4).z, (A4).z);       \
    (A4).w = fmaf((a), (B4).w, (A4).w);

// ---------------- split-K register-tiled GEMM ----------------
__global__ __launch_bounds__(256) void gemm_sk(
    const float* __restrict__ A1, int w1,
    const float* __restrict__ A2, int w2,
    const float* __restrict__ Bm, int N, int kper,
    float* __restrict__ Cpart)
{
    __shared__ float As[2][16][132];
    __shared__ float Bs[2][16][128];

    const int t  = threadIdx.x;
    const int tx = t & 15, ty = t >> 4;
    const int col0 = blockIdx.x * 128;
    const int k0   = blockIdx.z * kper;
    const int nsteps = kper >> 4;

    const int rowA = t >> 2;
    const int kcA  = (t & 3) * 4;
    const int kB0 = t >> 5,        nB0 = (t & 31) * 4;
    const int kB1 = (t + 256) >> 5, nB1 = (t & 31) * 4;

    float4 acc[2][2][4];
#pragma unroll
    for (int a = 0; a < 2; ++a)
#pragma unroll
        for (int b = 0; b < 2; ++b)
#pragma unroll
            for (int i = 0; i < 4; ++i) acc[a][b][i] = make_float4(0.f, 0.f, 0.f, 0.f);

    auto ldA4 = [&](int row, int k4) -> float4 {
        return (k4 < w1) ? *(const float4*)(A1 + (size_t)row * w1 + k4)
                         : *(const float4*)(A2 + (size_t)row * w2 + (k4 - w1));
    };

    {
        const float4 a0 = ldA4(rowA, k0 + kcA);
        const float4 a1 = ldA4(64 + rowA, k0 + kcA);
        const float4 b0 = *(const float4*)(Bm + (size_t)(k0 + kB0) * N + col0 + nB0);
        const float4 b1 = *(const float4*)(Bm + (size_t)(k0 + kB1) * N + col0 + nB1);
        const float* a0p = (const float*)&a0;
        const float* a1p = (const float*)&a1;
#pragma unroll
        for (int j = 0; j < 4; ++j) {
            As[0][kcA + j][rowA]      = a0p[j];
            As[0][kcA + j][64 + rowA] = a1p[j];
        }
        *(float4*)&Bs[0][kB0][nB0] = b0;
        *(float4*)&Bs[0][kB1][nB1] = b1;
    }
    __syncthreads();

    for (int s = 0; s < nsteps; ++s) {
        const int cur = s & 1, nxt = cur ^ 1;
        const bool more = (s + 1) < nsteps;
        float4 a0n, a1n, b0n, b1n;
        if (more) {
            const int kk = k0 + (s + 1) * 16;
            a0n = ldA4(rowA, kk + kcA);
            a1n = ldA4(64 + rowA, kk + kcA);
            b0n = *(const float4*)(Bm + (size_t)(kk + kB0) * N + col0 + nB0);
            b1n = *(const float4*)(Bm + (size_t)(kk + kB1) * N + col0 + nB1);
        }
#pragma unroll
        for (int k = 0; k < 16; ++k) {
            const float4 av0 = *(const float4*)&As[cur][k][ty * 4];
            const float4 av1 = *(const float4*)&As[cur][k][64 + ty * 4];
            const float4 bv0 = *(const float4*)&Bs[cur][k][tx * 4];
            const float4 bv1 = *(const float4*)&Bs[cur][k][64 + tx * 4];
            const float* a0p = (const float*)&av0;
            const float* a1p = (const float*)&av1;
#pragma unroll
            for (int i = 0; i < 4; ++i) {
                FMA4(acc[0][0][i], a0p[i], bv0);
                FMA4(acc[0][1][i], a0p[i], bv1);
                FMA4(acc[1][0][i], a1p[i], bv0);
                FMA4(acc[1][1][i], a1p[i], bv1);
            }
        }
        if (more) {
            const float* a0p = (const float*)&a0n;
            const float* a1p = (const float*)&a1n;
#pragma unroll
            for (int j = 0; j < 4; ++j) {
                As[nxt][kcA + j][rowA]      = a0p[j];
                As[nxt][kcA + j][64 + rowA] = a1p[j];
            }
            *(float4*)&Bs[nxt][kB0][nB0] = b0n;
            *(float4*)&Bs[nxt][kB1][nB1] = b1n;
        }
        __syncthreads();
    }

    float* Cp = Cpart + (size_t)blockIdx.z * 128 * (size_t)N;
#pragma unroll
    for (int a = 0; a < 2; ++a)
#pragma unroll
        for (int i = 0; i < 4; ++i) {
            const int row = a * 64 + ty * 4 + i;
#pragma unroll
            for (int b = 0; b < 2; ++b)
                *(float4*)(Cp + (size_t)row * N + col0 + b * 64 + tx * 4) = acc[a][b][i];
        }
}

// ---------------- split-K reduce (optionally tanh) ----------------
template <int P, int ACT>
__global__ __launch_bounds__(256) void reduce_sk(
    const float* __restrict__ part, float* __restrict__ out, int n)
{
    const int i4 = (blockIdx.x * 256 + threadIdx.x) * 4;
    float4 s = make_float4(0.f, 0.f, 0.f, 0.f);
#pragma unroll
    for (int p = 0; p < P; ++p) {
        const float4 v = *(const float4*)(part + (size_t)p * n + i4);
        s.x += v.x; s.y += v.y; s.z += v.z; s.w += v.w;
    }
    if (ACT) { s.x = tanhf(s.x); s.y = tanhf(s.y); s.z = tanhf(s.z); s.w = tanhf(s.w); }
    *(float4*)(out + i4) = s;
}

// ---------------- cell elementwise (fused gates split-K reduce) ----------------
__global__ __launch_bounds__(256) void cell_ew(
    const float* __restrict__ gpart,
    const float* __restrict__ bg,
    const float* __restrict__ c_tm1,
    float* __restrict__ out_h,
    float* __restrict__ out_c)
{
    const int i4 = (blockIdx.x * 256 + threadIdx.x) * 4;
    const int b  = i4 >> 10;
    const int h4 = i4 & 1023;

    float4 g[4];
#pragma unroll
    for (int gg = 0; gg < 4; ++gg) {
        float4 s = *(const float4*)(bg + gg * 1024 + h4);
#pragma unroll
        for (int p = 0; p < SK_G; ++p) {
            const float4 v = *(const float4*)(gpart + ((size_t)p * BB + b) * G4 + gg * 1024 + h4);
            s.x += v.x; s.y += v.y; s.z += v.z; s.w += v.w;
        }
        g[gg] = s;
    }
    const float4 c4 = *(const float4*)(c_tm1 + i4);
    const float* ip = (const float*)&g[0];
    const float* fp = (const float*)&g[1];
    const float* op = (const float*)&g[2];
    const float* gp = (const float*)&g[3];
    const float* cp = (const float*)&c4;
    float hv[4], cv[4];
#pragma unroll
    for (int j = 0; j < 4; ++j) {
        const float I = sigf(ip[j]);
        const float F = sigf(fp[j]);
        const float O = sigf(op[j]);
        const float G = sigf(gp[j]);
        const float c = sigf(F) * cp[j] + sigf(I) * tanhf(G);
        cv[j] = c;
        hv[j] = sigf(O) * tanhf(c);
    }
    *(float4*)(out_c + i4) = make_float4(cv[0], cv[1], cv[2], cv[3]);
    *(float4*)(out_h + i4) = make_float4(hv[0], hv[1], hv[2], hv[3]);
}

// ---------------- attention stage 1: online softmax, 4 rows/iter ----------------
__global__ __launch_bounds__(256, 2) void attn_partial(
    const float* __restrict__ ctx,
    const float* __restrict__ target,
    float* __restrict__ zpart,
    float* __restrict__ mdpart)
{
    const int b = blockIdx.x;
    const int chunk = blockIdx.y;
    const int wave = threadIdx.x >> 6;
    const int lane = threadIdx.x & 63;
    const int part = chunk * 4 + wave;

    const float* tg = target + (size_t)b * DD;
    float4 t4[4];
#pragma unroll
    for (int k = 0; k < 4; ++k) t4[k] = *(const float4*)(tg + lane * 4 + k * 256);

    float m = -INFINITY, denom = 0.f;
    float4 z[4];
#pragma unroll
    for (int k = 0; k < 4; ++k) z[k] = make_float4(0.f, 0.f, 0.f, 0.f);

    const int lbase = chunk * (LCTX / CHUNKS) + wave * 16;

    for (int r0 = 0; r0 < 16; r0 += RB) {
        float4 c[RB][4];
        float s[RB];
#pragma unroll
        for (int rr = 0; rr < RB; ++rr) {
            const float* cr = ctx + ((size_t)b * LCTX + lbase + r0 + rr) * DD;
#pragma unroll
            for (int k = 0; k < 4; ++k)
                c[rr][k] = *(const float4*)(cr + lane * 4 + k * 256);
        }
#pragma unroll
        for (int rr = 0; rr < RB; ++rr) {
            float ss = 0.f;
#pragma unroll
            for (int k = 0; k < 4; ++k) {
                ss = fmaf(c[rr][k].x, t4[k].x, ss);
                ss = fmaf(c[rr][k].y, t4[k].y, ss);
                ss = fmaf(c[rr][k].z, t4[k].z, ss);
                ss = fmaf(c[rr][k].w, t4[k].w, ss);
            }
            s[rr] = ss;
        }
#pragma unroll
        for (int off = 32; off; off >>= 1)
#pragma unroll
            for (int rr = 0; rr < RB; ++rr) s[rr] += __shfl_xor(s[rr], off);

        float mn = m;
#pragma unroll
        for (int rr = 0; rr < RB; ++rr) mn = fmaxf(mn, s[rr]);
        const float scale = __expf(m - mn);
        float w[RB];
        float ds = 0.f;
#pragma unroll
        for (int rr = 0; rr < RB; ++rr) { w[rr] = __expf(s[rr] - mn); ds += w[rr]; }
        denom = denom * scale + ds;
#pragma unroll
        for (int k = 0; k < 4; ++k) {
            z[k].x = z[k].x * scale + w[0]*c[0][k].x + w[1]*c[1][k].x + w[2]*c[2][k].x + w[3]*c[3][k].x;
            z[k].y = z[k].y * scale + w[0]*c[0][k].y + w[1]*c[1][k].y + w[2]*c[2][k].y + w[3]*c[3][k].y;
            z[k].z = z[k].z * scale + w[0]*c[0][k].z + w[1]*c[1][k].z + w[2]*c[2][k].z + w[3]*c[3][k].z;
            z[k].w = z[k].w * scale + w[0]*c[0][k].w + w[1]*c[1][k].w + w[2]*c[2][k].w + w[3]*c[3][k].w;
        }
        m = mn;
    }

    float* zp = zpart + ((size_t)b * NPART + part) * DD;
#pragma unroll
    for (int k = 0; k < 4; ++k)
        *(float4*)(zp + lane * 4 + k * 256) = z[k];
    if (lane == 0) {
        mdpart[((size_t)b * NPART + part) * 2 + 0] = m;
        mdpart[((size_t)b * NPART + part) * 2 + 1] = denom;
    }
}

// ---------------- attention stage 2: combine partials ----------------
__global__ __launch_bounds__(256) void attn_combine(
    const float* __restrict__ zpart,
    const float* __restrict__ mdpart,
    float* __restrict__ zout)
{
    const int b = blockIdx.x;
    const int tid = threadIdx.x;
    const float* md = mdpart + (size_t)b * NPART * 2;

    float M = -INFINITY;
#pragma unroll
    for (int p = 0; p < NPART; ++p) M = fmaxf(M, md[2 * p]);
    float sc[NPART];
    float den = 0.f;
#pragma unroll
    for (int p = 0; p < NPART; ++p) {
        sc[p] = __expf(md[2 * p] - M);
        den = fmaf(sc[p], md[2 * p + 1], den);
    }
    const float inv = 1.0f / den;

    const int d0 = tid * 4;
    float4 acc = make_float4(0.f, 0.f, 0.f, 0.f);
#pragma unroll
    for (int p = 0; p < NPART; ++p) {
        const float4 v = *(const float4*)(zpart + ((size_t)b * NPART + p) * DD + d0);
        acc.x = fmaf(sc[p], v.x, acc.x);
        acc.y = fmaf(sc[p], v.y, acc.y);
        acc.z = fmaf(sc[p], v.z, acc.z);
        acc.w = fmaf(sc[p], v.w, acc.w);
    }
    acc.x *= inv; acc.y *= inv; acc.z *= inv; acc.w *= inv;
    *(float4*)(zout + (size_t)b * DD + d0) = acc;
}

extern "C" void kernel_launch(void* const* d_in, const int* in_sizes, int n_in,
                              void* d_out, int out_size, void* d_ws, size_t ws_size,
                              hipStream_t stream) {
    const float* x       = (const float*)d_in[0];
    const float* out_tm1 = (const float*)d_in[1];
    const float* c_tm1   = (const float*)d_in[3];
    const float* ctx     = (const float*)d_in[4];
    const float* Wg      = (const float*)d_in[5];
    const float* bg      = (const float*)d_in[6];
    const float* Wt      = (const float*)d_in[7];
    const float* Wo      = (const float*)d_in[8];

    float* out = (float*)d_out;
    float* o_output = out;
    float* o_h      = out + BB * NH;
    float* o_c      = out + 2 * BB * NH;

    float* ws = (float*)d_ws;
    float* ws_gpart  = ws;
    float* ws_tpart  = ws_gpart + (size_t)SK_G * BB * G4;
    float* ws_target = ws_tpart + (size_t)SK_T * BB * NH;
    float* ws_opart  = ws_target + (size_t)BB * NH;
    float* ws_zpart  = ws_opart + (size_t)SK_O * BB * NH;
    float* ws_md     = ws_zpart + (size_t)BB * NPART * DD;
    float* ws_z      = ws_md + (size_t)BB * NPART * 2;

    // A/B experiment: run the identical chain TWICE.
    // dur(round4) - dur(round3) = marginal cost of one full chain (kernels + dispatch),
    // 2*dur(round3) - dur(round4) = fixed per-call overhead inside dur_us.
    // Pass 2 recomputes identical values (deterministic fp32) -> output unchanged.
    for (int rep = 0; rep < 2; ++rep) {
        gemm_sk<<<dim3(G4 / 128, 1, SK_G), 256, 0, stream>>>(x, NIN, out_tm1, NH, Wg, G4, KG / SK_G, ws_gpart);
        cell_ew<<<dim3(BB * NH / 1024), 256, 0, stream>>>(ws_gpart, bg, c_tm1, o_h, o_c);
        gemm_sk<<<dim3(NH / 128, 1, SK_T), 256, 0, stream>>>(o_h, NH, nullptr, 0, Wt, NH, NH / SK_T, ws_tpart);
        reduce_sk<SK_T, 0><<<dim3(BB * NH / 1024), 256, 0, stream>>>(ws_tpart, ws_target, BB * NH);
        attn_partial<<<dim3(BB, CHUNKS), 256, 0, stream>>>(ctx, ws_target, ws_zpart, ws_md);
        attn_combine<<<dim3(BB), 256, 0, stream>>>(ws_zpart, ws_md, ws_z);
        gemm_sk<<<dim3(NH / 128, 1, SK_O), 256, 0, stream>>>(o_h, NH, ws_z, DD, Wo, NH, KO / SK_O, ws_opart);
        reduce_sk<SK_O, 1><<<dim3(BB * NH / 1024), 256, 0, stream>>>(ws_opart, o_output, BB * NH);
    }
}

// Round 6
// 465.181 us; speedup vs baseline: 1.3100x; 1.3100x over previous
//
#include <hip/hip_runtime.h>
#include <math.h>

#define BB   128
#define NIN  512
#define NH   1024
#define LCTX 512
#define DD   1024
#define G4   4096
#define KG   1536
#define KO   2048

#define SK_G 8
#define SK_T 16
#define SK_O 16

#define CHUNKS 8
#define NPART  (CHUNKS * 4)
#define RB 4

__device__ __forceinline__ float sigf(float x) { return 1.0f / (1.0f + __expf(-x)); }

#define FMA4(A4, a, B4)                       \
    (A4).x = fmaf((a), (B4).x, (A4).x);       \
    (A4).y = fmaf((a), (B4).y, (A4).y);       \
    (A4).z = fmaf((a), (B4).z, (A4).z);       \
    (A4).w = fmaf((a), (B4).w, (A4).w);

// ---------------- split-K register-tiled GEMM ----------------
// BM=128 (all of M), BN=64, BK=16, 256 threads.
// Per thread: 2 row-quadrants x 4 rows x 4 cols = 32 outputs.
// Inner loop: 3 ds_read_b128 per 32 v_fma -> VALU-bound, conflict-free.
__global__ __launch_bounds__(256) void gemm_sk(
    const float* __restrict__ A1, int w1,
    const float* __restrict__ A2, int w2,
    const float* __restrict__ Bm, int N, int kper,
    float* __restrict__ Cpart)
{
    __shared__ float As[2][16][132];   // [k][m], m padded to 132
    __shared__ float Bs[2][16][64];    // [k][n]

    const int t  = threadIdx.x;
    const int tx = t & 15, ty = t >> 4;
    const int col0 = blockIdx.x * 64;
    const int k0   = blockIdx.z * kper;
    const int nsteps = kper >> 4;

    // A staging: 128 rows x 16 k = 2048 elems; 2 float4/thread along k
    const int rowA = t >> 1;           // 0..127
    const int kcA  = (t & 1) * 8;      // 0 or 8 (two float4: kcA, kcA+4)
    // B staging: 16 k x 64 n = 1024 elems; 1 float4/thread
    const int kB = t >> 4;             // 0..15
    const int nB = (t & 15) * 4;

    float4 acc[2][4];
#pragma unroll
    for (int a = 0; a < 2; ++a)
#pragma unroll
        for (int i = 0; i < 4; ++i) acc[a][i] = make_float4(0.f, 0.f, 0.f, 0.f);

    auto ldA4 = [&](int row, int k4) -> float4 {
        return (k4 < w1) ? *(const float4*)(A1 + (size_t)row * w1 + k4)
                         : *(const float4*)(A2 + (size_t)row * w2 + (k4 - w1));
    };

    // prologue: stage step 0
    {
        const float4 a0 = ldA4(rowA, k0 + kcA);
        const float4 a1 = ldA4(rowA, k0 + kcA + 4);
        const float4 b0 = *(const float4*)(Bm + (size_t)(k0 + kB) * N + col0 + nB);
        const float* a0p = (const float*)&a0;
        const float* a1p = (const float*)&a1;
#pragma unroll
        for (int j = 0; j < 4; ++j) {
            As[0][kcA + j][rowA]     = a0p[j];
            As[0][kcA + 4 + j][rowA] = a1p[j];
        }
        *(float4*)&Bs[0][kB][nB] = b0;
    }
    __syncthreads();

    for (int s = 0; s < nsteps; ++s) {
        const int cur = s & 1, nxt = cur ^ 1;
        const bool more = (s + 1) < nsteps;
        float4 a0n, a1n, b0n;
        if (more) {
            const int kk = k0 + (s + 1) * 16;
            a0n = ldA4(rowA, kk + kcA);
            a1n = ldA4(rowA, kk + kcA + 4);
            b0n = *(const float4*)(Bm + (size_t)(kk + kB) * N + col0 + nB);
        }
#pragma unroll
        for (int k = 0; k < 16; ++k) {
            const float4 av0 = *(const float4*)&As[cur][k][ty * 4];
            const float4 av1 = *(const float4*)&As[cur][k][64 + ty * 4];
            const float4 bv  = *(const float4*)&Bs[cur][k][tx * 4];
            const float* a0p = (const float*)&av0;
            const float* a1p = (const float*)&av1;
#pragma unroll
            for (int i = 0; i < 4; ++i) {
                FMA4(acc[0][i], a0p[i], bv);
                FMA4(acc[1][i], a1p[i], bv);
            }
        }
        if (more) {
            const float* a0p = (const float*)&a0n;
            const float* a1p = (const float*)&a1n;
#pragma unroll
            for (int j = 0; j < 4; ++j) {
                As[nxt][kcA + j][rowA]     = a0p[j];
                As[nxt][kcA + 4 + j][rowA] = a1p[j];
            }
            *(float4*)&Bs[nxt][kB][nB] = b0n;
        }
        __syncthreads();
    }

    float* Cp = Cpart + (size_t)blockIdx.z * 128 * (size_t)N;
#pragma unroll
    for (int a = 0; a < 2; ++a)
#pragma unroll
        for (int i = 0; i < 4; ++i) {
            const int row = a * 64 + ty * 4 + i;
            *(float4*)(Cp + (size_t)row * N + col0 + tx * 4) = acc[a][i];
        }
}

// ---------------- split-K reduce (optionally tanh) ----------------
template <int P, int ACT>
__global__ __launch_bounds__(256) void reduce_sk(
    const float* __restrict__ part, float* __restrict__ out, int n)
{
    const int i4 = (blockIdx.x * 256 + threadIdx.x) * 4;
    float4 s = make_float4(0.f, 0.f, 0.f, 0.f);
#pragma unroll
    for (int p = 0; p < P; ++p) {
        const float4 v = *(const float4*)(part + (size_t)p * n + i4);
        s.x += v.x; s.y += v.y; s.z += v.z; s.w += v.w;
    }
    if (ACT) { s.x = tanhf(s.x); s.y = tanhf(s.y); s.z = tanhf(s.z); s.w = tanhf(s.w); }
    *(float4*)(out + i4) = s;
}

// ---------------- cell elementwise (fused gates split-K reduce) ----------------
__global__ __launch_bounds__(256) void cell_ew(
    const float* __restrict__ gpart,  // [SK_G][B][4H] pre-activation partials
    const float* __restrict__ bg,
    const float* __restrict__ c_tm1,
    float* __restrict__ out_h,
    float* __restrict__ out_c)
{
    const int i4 = (blockIdx.x * 256 + threadIdx.x) * 4;
    const int b  = i4 >> 10;
    const int h4 = i4 & 1023;

    float4 g[4];
#pragma unroll
    for (int gg = 0; gg < 4; ++gg) {
        float4 s = *(const float4*)(bg + gg * 1024 + h4);
#pragma unroll
        for (int p = 0; p < SK_G; ++p) {
            const float4 v = *(const float4*)(gpart + ((size_t)p * BB + b) * G4 + gg * 1024 + h4);
            s.x += v.x; s.y += v.y; s.z += v.z; s.w += v.w;
        }
        g[gg] = s;
    }
    const float4 c4 = *(const float4*)(c_tm1 + i4);
    const float* ip = (const float*)&g[0];
    const float* fp = (const float*)&g[1];
    const float* op = (const float*)&g[2];
    const float* gp = (const float*)&g[3];
    const float* cp = (const float*)&c4;
    float hv[4], cv[4];
#pragma unroll
    for (int j = 0; j < 4; ++j) {
        const float I = sigf(ip[j]);
        const float F = sigf(fp[j]);
        const float O = sigf(op[j]);
        const float G = sigf(gp[j]);
        const float c = sigf(F) * cp[j] + sigf(I) * tanhf(G);
        cv[j] = c;
        hv[j] = sigf(O) * tanhf(c);
    }
    *(float4*)(out_c + i4) = make_float4(cv[0], cv[1], cv[2], cv[3]);
    *(float4*)(out_h + i4) = make_float4(hv[0], hv[1], hv[2], hv[3]);
}

// ---------------- attention stage 1: online softmax, 4 rows/iter ----------------
__global__ __launch_bounds__(256, 2) void attn_partial(
    const float* __restrict__ ctx,
    const float* __restrict__ target,
    float* __restrict__ zpart,
    float* __restrict__ mdpart)
{
    const int b = blockIdx.x;
    const int chunk = blockIdx.y;
    const int wave = threadIdx.x >> 6;
    const int lane = threadIdx.x & 63;
    const int part = chunk * 4 + wave;

    const float* tg = target + (size_t)b * DD;
    float4 t4[4];
#pragma unroll
    for (int k = 0; k < 4; ++k) t4[k] = *(const float4*)(tg + lane * 4 + k * 256);

    float m = -INFINITY, denom = 0.f;
    float4 z[4];
#pragma unroll
    for (int k = 0; k < 4; ++k) z[k] = make_float4(0.f, 0.f, 0.f, 0.f);

    const int lbase = chunk * (LCTX / CHUNKS) + wave * 16;

    for (int r0 = 0; r0 < 16; r0 += RB) {
        float4 c[RB][4];
        float s[RB];
#pragma unroll
        for (int rr = 0; rr < RB; ++rr) {
            const float* cr = ctx + ((size_t)b * LCTX + lbase + r0 + rr) * DD;
#pragma unroll
            for (int k = 0; k < 4; ++k)
                c[rr][k] = *(const float4*)(cr + lane * 4 + k * 256);
        }
#pragma unroll
        for (int rr = 0; rr < RB; ++rr) {
            float ss = 0.f;
#pragma unroll
            for (int k = 0; k < 4; ++k) {
                ss = fmaf(c[rr][k].x, t4[k].x, ss);
                ss = fmaf(c[rr][k].y, t4[k].y, ss);
                ss = fmaf(c[rr][k].z, t4[k].z, ss);
                ss = fmaf(c[rr][k].w, t4[k].w, ss);
            }
            s[rr] = ss;
        }
#pragma unroll
        for (int off = 32; off; off >>= 1)
#pragma unroll
            for (int rr = 0; rr < RB; ++rr) s[rr] += __shfl_xor(s[rr], off);

        float mn = m;
#pragma unroll
        for (int rr = 0; rr < RB; ++rr) mn = fmaxf(mn, s[rr]);
        const float scale = __expf(m - mn);
        float w[RB];
        float ds = 0.f;
#pragma unroll
        for (int rr = 0; rr < RB; ++rr) { w[rr] = __expf(s[rr] - mn); ds += w[rr]; }
        denom = denom * scale + ds;
#pragma unroll
        for (int k = 0; k < 4; ++k) {
            z[k].x = z[k].x * scale + w[0]*c[0][k].x + w[1]*c[1][k].x + w[2]*c[2][k].x + w[3]*c[3][k].x;
            z[k].y = z[k].y * scale + w[0]*c[0][k].y + w[1]*c[1][k].y + w[2]*c[2][k].y + w[3]*c[3][k].y;
            z[k].z = z[k].z * scale + w[0]*c[0][k].z + w[1]*c[1][k].z + w[2]*c[2][k].z + w[3]*c[3][k].z;
            z[k].w = z[k].w * scale + w[0]*c[0][k].w + w[1]*c[1][k].w + w[2]*c[2][k].w + w[3]*c[3][k].w;
        }
        m = mn;
    }

    float* zp = zpart + ((size_t)b * NPART + part) * DD;
#pragma unroll
    for (int k = 0; k < 4; ++k)
        *(float4*)(zp + lane * 4 + k * 256) = z[k];
    if (lane == 0) {
        mdpart[((size_t)b * NPART + part) * 2 + 0] = m;
        mdpart[((size_t)b * NPART + part) * 2 + 1] = denom;
    }
}

// ---------------- attention stage 2: combine partials ----------------
__global__ __launch_bounds__(256) void attn_combine(
    const float* __restrict__ zpart,
    const float* __restrict__ mdpart,
    float* __restrict__ zout)
{
    const int b = blockIdx.x;
    const int tid = threadIdx.x;
    const float* md = mdpart + (size_t)b * NPART * 2;

    float M = -INFINITY;
#pragma unroll
    for (int p = 0; p < NPART; ++p) M = fmaxf(M, md[2 * p]);
    float sc[NPART];
    float den = 0.f;
#pragma unroll
    for (int p = 0; p < NPART; ++p) {
        sc[p] = __expf(md[2 * p] - M);
        den = fmaf(sc[p], md[2 * p + 1], den);
    }
    const float inv = 1.0f / den;

    const int d0 = tid * 4;
    float4 acc = make_float4(0.f, 0.f, 0.f, 0.f);
#pragma unroll
    for (int p = 0; p < NPART; ++p) {
        const float4 v = *(const float4*)(zpart + ((size_t)b * NPART + p) * DD + d0);
        acc.x = fmaf(sc[p], v.x, acc.x);
        acc.y = fmaf(sc[p], v.y, acc.y);
        acc.z = fmaf(sc[p], v.z, acc.z);
        acc.w = fmaf(sc[p], v.w, acc.w);
    }
    acc.x *= inv; acc.y *= inv; acc.z *= inv; acc.w *= inv;
    *(float4*)(zout + (size_t)b * DD + d0) = acc;
}

extern "C" void kernel_launch(void* const* d_in, const int* in_sizes, int n_in,
                              void* d_out, int out_size, void* d_ws, size_t ws_size,
                              hipStream_t stream) {
    const float* x       = (const float*)d_in[0];
    const float* out_tm1 = (const float*)d_in[1];
    // d_in[2] = h_tm1 unused by the reference
    const float* c_tm1   = (const float*)d_in[3];
    const float* ctx     = (const float*)d_in[4];
    const float* Wg      = (const float*)d_in[5];
    const float* bg      = (const float*)d_in[6];
    const float* Wt      = (const float*)d_in[7];
    const float* Wo      = (const float*)d_in[8];

    float* out = (float*)d_out;
    float* o_output = out;
    float* o_h      = out + BB * NH;
    float* o_c      = out + 2 * BB * NH;

    float* ws = (float*)d_ws;
    float* ws_gpart  = ws;                                    // SK_G*128*4096
    float* ws_tpart  = ws_gpart + (size_t)SK_G * BB * G4;     // SK_T*128*1024
    float* ws_target = ws_tpart + (size_t)SK_T * BB * NH;     // 128*1024
    float* ws_opart  = ws_target + (size_t)BB * NH;           // SK_O*128*1024
    float* ws_zpart  = ws_opart + (size_t)SK_O * BB * NH;     // 128*32*1024
    float* ws_md     = ws_zpart + (size_t)BB * NPART * DD;    // 128*32*2
    float* ws_z      = ws_md + (size_t)BB * NPART * 2;        // 128*1024

    // 1) gates partials = concat(x, out_tm1) @ Wg   (split-K 8, BN=64 -> 512 blocks)
    gemm_sk<<<dim3(G4 / 64, 1, SK_G), 256, 0, stream>>>(x, NIN, out_tm1, NH, Wg, G4, KG / SK_G, ws_gpart);
    // 2) reduce + bias + activations -> h_t, c_t
    cell_ew<<<dim3(BB * NH / 1024), 256, 0, stream>>>(ws_gpart, bg, c_tm1, o_h, o_c);
    // 3) target partials = h_t @ Wt (split-K 16 -> 256 blocks), then reduce
    gemm_sk<<<dim3(NH / 64, 1, SK_T), 256, 0, stream>>>(o_h, NH, nullptr, 0, Wt, NH, NH / SK_T, ws_tpart);
    reduce_sk<SK_T, 0><<<dim3(BB * NH / 1024), 256, 0, stream>>>(ws_tpart, ws_target, BB * NH);
    // 4) attention (single ctx pass, online softmax)
    attn_partial<<<dim3(BB, CHUNKS), 256, 0, stream>>>(ctx, ws_target, ws_zpart, ws_md);
    attn_combine<<<dim3(BB), 256, 0, stream>>>(ws_zpart, ws_md, ws_z);
    // 5) output partials = concat(h_t, z) @ Wo (split-K 16 -> 256 blocks), reduce + tanh
    gemm_sk<<<dim3(NH / 64, 1, SK_O), 256, 0, stream>>>(o_h, NH, ws_z, DD, Wo, NH, KO / SK_O, ws_opart);
    reduce_sk<SK_O, 1><<<dim3(BB * NH / 1024), 256, 0, stream>>>(ws_opart, o_output, BB * NH);
}